// Round 5
// baseline (288.009 us; speedup 1.0000x reference)
//
#include <hip/hip_runtime.h>
#include <hip/hip_bf16.h>

#define CDIV(a,b) (((a)+(b)-1)/(b))
#define NBUCK_MAX 512   // buckets of 128 nodes; supports N up to 65536 (ebuf packing needs N<=65536)

typedef __attribute__((ext_vector_type(8))) short short8;
typedef __attribute__((ext_vector_type(4))) float f32x4;

static __device__ __forceinline__ unsigned short f2bf(float f){
  union { float f; unsigned u; } v; v.f = f;
  unsigned r = v.u + 0x7fffu + ((v.u >> 16) & 1u);   // RNE
  return (unsigned short)(r >> 16);
}
static __device__ __forceinline__ unsigned pack2(float lo, float hi){
  return (unsigned)f2bf(lo) | ((unsigned)f2bf(hi) << 16);
}
static __device__ __forceinline__ float bfu_lo(unsigned u){
  union { unsigned u; float f; } v; v.u = u << 16; return v.f;
}
static __device__ __forceinline__ float bfu_hi(unsigned u){
  union { unsigned u; float f; } v; v.u = u & 0xffff0000u; return v.f;
}
static __device__ __forceinline__ float bf2f(unsigned short s){
  union { unsigned u; float f; } v; v.u = ((unsigned)s) << 16; return v.f;
}

// ---------------- prep: cast x->bf16 (blocks [0,castBlocks)) + bucket histogram (rest) ----------------

__global__ __launch_bounds__(256) void k_prep(const float* __restrict__ x, int n2, unsigned* __restrict__ xb,
                                              const int* __restrict__ dst, int E,
                                              int* __restrict__ bcnt, int nbuck, int castBlocks){
  __shared__ int s[NBUCK_MAX];
  int b = blockIdx.x, t = threadIdx.x;
  if (b < castBlocks){
    int i = b*256 + t;
    if (i < n2){
      float2 v = ((const float2*)x)[i];
      xb[i] = pack2(v.x, v.y);
    }
    return;
  }
  for (int i=t;i<nbuck;i+=256) s[i] = 0;
  __syncthreads();
  constexpr int EPT = 16;
  int e0 = (b - castBlocks)*256*EPT;
  #pragma unroll
  for (int i=0;i<EPT;i++){
    int e = e0 + i*256 + t;
    if (e < E) atomicAdd(&s[dst[e] >> 7], 1);
  }
  __syncthreads();
  for (int i=t;i<nbuck;i+=256){
    int c = s[i];
    if (c > 0) atomicAdd(&bcnt[i], c);
  }
}

// single block: exclusive scan of bcnt[0..nbuck) -> bbase[0..nbuck], bbase[nbuck]=E
__global__ __launch_bounds__(256) void k_bscan(const int* __restrict__ bcnt, int nbuck,
                                               int* __restrict__ bbase){
  __shared__ int s[256];
  int t = threadIdx.x;
  int a0 = (2*t   < nbuck) ? bcnt[2*t]   : 0;
  int a1 = (2*t+1 < nbuck) ? bcnt[2*t+1] : 0;
  s[t] = a0 + a1; __syncthreads();
  for (int d=1; d<256; d<<=1){
    int u = (t>=d) ? s[t-d] : 0;
    __syncthreads();
    s[t] += u;
    __syncthreads();
  }
  int excl = s[t] - (a0 + a1);
  if (2*t   < nbuck) bbase[2*t]   = excl;
  if (2*t+1 < nbuck) bbase[2*t+1] = excl + a0;
  if (t == 255) bbase[nbuck] = s[255];
}

// Pass A: bin edges into 128-node buckets; bucket region in ebuf == final csr region.
// Packed entry: (local_dst << 16) | src  (requires N <= 65536)
__global__ __launch_bounds__(256) void k_bucketA(const int* __restrict__ src, const int* __restrict__ dst,
                                                 int E, const int* __restrict__ bbase,
                                                 int* __restrict__ bcur, unsigned* __restrict__ ebuf, int nbuck){
  __shared__ int scnt[NBUCK_MAX];
  __shared__ int sbase[NBUCK_MAX];
  __shared__ int sboff[NBUCK_MAX];
  int t = threadIdx.x;
  for (int i=t;i<nbuck;i+=256) scnt[i] = 0;
  __syncthreads();
  constexpr int EPT = 16;
  int e0 = blockIdx.x*256*EPT;
  int b[EPT]; unsigned pk[EPT];
  #pragma unroll
  for (int i=0;i<EPT;i++){
    int e = e0 + i*256 + t;
    if (e < E){
      int d = dst[e];
      b[i] = d >> 7;
      pk[i] = ((unsigned)(d & 127) << 16) | (unsigned)src[e];
      atomicAdd(&scnt[b[i]], 1);
    } else b[i] = -1;
  }
  __syncthreads();
  for (int i=t;i<nbuck;i+=256){
    int c = scnt[i];
    sbase[i] = (c > 0) ? atomicAdd(&bcur[i], c) : 0;
    sboff[i] = bbase[i];
    scnt[i] = 0;
  }
  __syncthreads();
  #pragma unroll
  for (int i=0;i<EPT;i++){
    if (b[i] >= 0){
      int p = atomicAdd(&scnt[b[i]], 1);
      ebuf[(size_t)sboff[b[i]] + sbase[b[i]] + p] = pk[i];
    }
  }
}

// Pass B: one block per bucket; local degree count + scan -> off + csr scatter in ~8KB window.
__global__ __launch_bounds__(256) void k_bucketB(const unsigned* __restrict__ ebuf, const int* __restrict__ bbase,
                                                 int N, int* __restrict__ off, int* __restrict__ csr){
  int b = blockIdx.x;
  int n0 = b << 7, n1 = min(n0 + 128, N);
  __shared__ int sdeg[128];
  __shared__ int sabs[129];
  __shared__ int cur[128];
  int t = threadIdx.x;
  if (t < 128){ sdeg[t] = 0; cur[t] = 0; }
  __syncthreads();
  int e0 = bbase[b], e1 = bbase[b+1];
  for (int e = e0 + t; e < e1; e += 256)
    atomicAdd(&sdeg[ebuf[e] >> 16], 1);
  __syncthreads();
  for (int d=1; d<128; d<<=1){
    int u = (t < 128 && t >= d) ? sdeg[t-d] : 0;
    __syncthreads();
    if (t < 128) sdeg[t] += u;
    __syncthreads();
  }
  if (t == 0) sabs[0] = e0;
  if (t < 128) sabs[t+1] = e0 + sdeg[t];
  __syncthreads();
  if (t <= n1 - n0) off[n0 + t] = sabs[t];
  for (int e = e0 + t; e < e1; e += 256){
    unsigned pr = ebuf[e];
    int ln = (int)(pr >> 16);
    int p = atomicAdd(&cur[ln], 1);
    csr[sabs[ln] + p] = (int)(pr & 0xffffu);
  }
}

// ---------------- weight pack: B-fragment order bf16 (+ optional BN scale/shift) ----------------

struct WtpArgs {
  const float *W0, *W1, *bl, *g, *b, *rm, *rv;
  unsigned short* Bpk; float *sc; float *sh;
  int kblk, dout, do_bn, nblk;
};

static __device__ __forceinline__ void wtp_one(const WtpArgs& a, int idx){
  int NB16 = a.kblk*32*a.dout;
  if (idx < NB16){
    int j = idx & 7, lane = (idx >> 3) & 63, rest = idx >> 9;
    int NT = a.dout >> 4;
    int nt = rest % NT, kk = rest / NT;
    int nn = nt*16 + (lane & 15);
    int k  = kk*32 + ((lane >> 4) * 8) + j;
    float v = (k < 128) ? a.W0[nn*128 + k] : a.W1[nn*128 + (k - 128)];
    a.Bpk[idx] = f2bf(v);
  } else if (a.do_bn && idx < NB16 + a.dout){
    int jj = idx - NB16;
    float s = a.g[jj] * rsqrtf(a.rv[jj] + 1e-5f);
    a.sc[jj] = s;
    a.sh[jj] = (a.bl[jj] - a.rm[jj]) * s + a.b[jj];
  }
}

__global__ __launch_bounds__(256) void k_wtp_all(WtpArgs a0, WtpArgs a1, WtpArgs a2, WtpArgs a3){
  int b = blockIdx.x, t = threadIdx.x;
  if (b < a0.nblk){ wtp_one(a0, b*256 + t); return; }
  b -= a0.nblk;
  if (b < a1.nblk){ wtp_one(a1, b*256 + t); return; }
  b -= a1.nblk;
  if (b < a2.nblk){ wtp_one(a2, b*256 + t); return; }
  b -= a2.nblk;
  wtp_one(a3, b*256 + t);
}

// ---------------- mean aggregation: software-pipelined gather (8 rows in flight/quad) ----------------

#define ACC8(v) { a0 += bfu_lo(v.x); a1 += bfu_hi(v.x); a2 += bfu_lo(v.y); a3 += bfu_hi(v.y); \
                  a4 += bfu_lo(v.z); a5 += bfu_hi(v.z); a6 += bfu_lo(v.w); a7 += bfu_hi(v.w); }

// 128-dim rows: 4 nodes/wave, 16 lanes x uint4 per row
__global__ __launch_bounds__(256) void k_agg(const uint4* __restrict__ hin4, const int* __restrict__ off,
                                             const int* __restrict__ csr, int n, uint4* __restrict__ mean4){
  int tid = blockIdx.x*256 + threadIdx.x;
  int lane = threadIdx.x & 63;
  int sl = lane & 15;
  int node = (tid >> 6)*4 + (lane >> 4);
  bool valid = node < n;
  int s0 = valid ? off[node]   : 0;
  int s1 = valid ? off[node+1] : 0;
  float a0=0,a1=0,a2=0,a3=0,a4=0,a5=0,a6=0,a7=0;
  int e = s0, rem = s1 - s0;

  uint4 vA0,vA1,vA2,vA3;
  int cA = rem < 4 ? rem : 4;
  if (cA > 0) vA0 = hin4[(size_t)csr[e  ]*16 + sl];
  if (cA > 1) vA1 = hin4[(size_t)csr[e+1]*16 + sl];
  if (cA > 2) vA2 = hin4[(size_t)csr[e+2]*16 + sl];
  if (cA > 3) vA3 = hin4[(size_t)csr[e+3]*16 + sl];
  e += 4; rem -= cA;

  while (rem > 0){
    int cB = rem < 4 ? rem : 4;
    uint4 vB0,vB1,vB2,vB3;
    if (cB > 0) vB0 = hin4[(size_t)csr[e  ]*16 + sl];
    if (cB > 1) vB1 = hin4[(size_t)csr[e+1]*16 + sl];
    if (cB > 2) vB2 = hin4[(size_t)csr[e+2]*16 + sl];
    if (cB > 3) vB3 = hin4[(size_t)csr[e+3]*16 + sl];
    e += 4; rem -= cB;
    if (cA > 0) ACC8(vA0);
    if (cA > 1) ACC8(vA1);
    if (cA > 2) ACC8(vA2);
    if (cA > 3) ACC8(vA3);
    vA0 = vB0; vA1 = vB1; vA2 = vB2; vA3 = vB3; cA = cB;
  }
  if (cA > 0) ACC8(vA0);
  if (cA > 1) ACC8(vA1);
  if (cA > 2) ACC8(vA2);
  if (cA > 3) ACC8(vA3);

  if (valid){
    int d = s1 - s0;
    float inv = 1.0f / (float)(d > 0 ? d : 1);
    uint4 o;
    o.x = pack2(a0*inv, a1*inv);
    o.y = pack2(a2*inv, a3*inv);
    o.z = pack2(a4*inv, a5*inv);
    o.w = pack2(a6*inv, a7*inv);
    mean4[(size_t)node*16 + sl] = o;
  }
}

// 64-dim rows: 8 nodes/wave, 8 lanes x uint4 per row
__global__ __launch_bounds__(256) void k_agg64(const uint4* __restrict__ hin4, const int* __restrict__ off,
                                               const int* __restrict__ csr, int n, uint4* __restrict__ mean4){
  int tid = blockIdx.x*256 + threadIdx.x;
  int lane = threadIdx.x & 63;
  int sl = lane & 7;
  int node = (tid >> 6)*8 + (lane >> 3);
  bool valid = node < n;
  int s0 = valid ? off[node]   : 0;
  int s1 = valid ? off[node+1] : 0;
  float a0=0,a1=0,a2=0,a3=0,a4=0,a5=0,a6=0,a7=0;
  int e = s0, rem = s1 - s0;

  uint4 vA0,vA1,vA2,vA3;
  int cA = rem < 4 ? rem : 4;
  if (cA > 0) vA0 = hin4[(size_t)csr[e  ]*8 + sl];
  if (cA > 1) vA1 = hin4[(size_t)csr[e+1]*8 + sl];
  if (cA > 2) vA2 = hin4[(size_t)csr[e+2]*8 + sl];
  if (cA > 3) vA3 = hin4[(size_t)csr[e+3]*8 + sl];
  e += 4; rem -= cA;

  while (rem > 0){
    int cB = rem < 4 ? rem : 4;
    uint4 vB0,vB1,vB2,vB3;
    if (cB > 0) vB0 = hin4[(size_t)csr[e  ]*8 + sl];
    if (cB > 1) vB1 = hin4[(size_t)csr[e+1]*8 + sl];
    if (cB > 2) vB2 = hin4[(size_t)csr[e+2]*8 + sl];
    if (cB > 3) vB3 = hin4[(size_t)csr[e+3]*8 + sl];
    e += 4; rem -= cB;
    if (cA > 0) ACC8(vA0);
    if (cA > 1) ACC8(vA1);
    if (cA > 2) ACC8(vA2);
    if (cA > 3) ACC8(vA3);
    vA0 = vB0; vA1 = vB1; vA2 = vB2; vA3 = vB3; cA = cB;
  }
  if (cA > 0) ACC8(vA0);
  if (cA > 1) ACC8(vA1);
  if (cA > 2) ACC8(vA2);
  if (cA > 3) ACC8(vA3);

  if (valid){
    int d = s1 - s0;
    float inv = 1.0f / (float)(d > 0 ? d : 1);
    uint4 o;
    o.x = pack2(a0*inv, a1*inv);
    o.y = pack2(a2*inv, a3*inv);
    o.z = pack2(a4*inv, a5*inv);
    o.w = pack2(a6*inv, a7*inv);
    mean4[(size_t)node*8 + sl] = o;
  }
}

// ---------------- bf16 MFMA GEMM, no LDS (B panel is L1/L2-resident), 3 modes ----------------
// MODE 0: hidden  — C = [A0|A1]@B (KBLK=8), BN+ReLU, bf16 out
// MODE 1: final   — C = A0@B (KBLK=4), += addb, BN, row-L2-normalize, f32 out
// MODE 2: linear  — C = A0@B (KBLK=4), bf16 out (no BN/ReLU)

template<int DOUT, int KBLK, int MODE>
__global__ __launch_bounds__(256, 4) void k_gemm_mfma(
    const unsigned short* __restrict__ A0, const unsigned short* __restrict__ A1,
    const unsigned short* __restrict__ Bpk, const float* __restrict__ sc,
    const float* __restrict__ sh, const unsigned short* __restrict__ addb,
    float* __restrict__ outf, unsigned short* __restrict__ outb, int n){
  constexpr int NT = DOUT/16;
  int t = threadIdx.x;
  int lane = t & 63, w = t >> 6;
  int quad = lane >> 4, c = lane & 15;
  int m_base = blockIdx.x*128 + w*32;
  int r0 = m_base + c;
  int r1 = r0 + 16;

  f32x4 acc[2][NT];
  #pragma unroll
  for (int mt=0;mt<2;mt++)
    #pragma unroll
    for (int nt=0;nt<NT;nt++) acc[mt][nt] = (f32x4){0.f,0.f,0.f,0.f};

  #pragma unroll
  for (int kk=0; kk<KBLK; kk++){
    const unsigned short* ab = (KBLK == 8 && kk >= 4) ? A1 : A0;
    int ka = (kk & 3)*32 + quad*8;
    short8 a0 = {0,0,0,0,0,0,0,0}, a1 = {0,0,0,0,0,0,0,0};
    if (r0 < n) a0 = *(const short8*)(ab + (size_t)r0*128 + ka);
    if (r1 < n) a1 = *(const short8*)(ab + (size_t)r1*128 + ka);
    #pragma unroll
    for (int nt=0; nt<NT; nt++){
      short8 b = *(const short8*)(Bpk + (size_t)((kk*NT + nt)*64 + lane)*8);
      acc[0][nt] = __builtin_amdgcn_mfma_f32_16x16x32_bf16(a0, b, acc[0][nt], 0, 0, 0);
      acc[1][nt] = __builtin_amdgcn_mfma_f32_16x16x32_bf16(a1, b, acc[1][nt], 0, 0, 0);
    }
  }

  float scv[NT], shv[NT];
  if constexpr (MODE != 2){
    #pragma unroll
    for (int nt=0;nt<NT;nt++){ scv[nt] = sc[nt*16 + c]; shv[nt] = sh[nt*16 + c]; }
  }

  #pragma unroll
  for (int mt=0; mt<2; mt++){
    #pragma unroll
    for (int r=0;r<4;r++){
      int row = m_base + mt*16 + quad*4 + r;
      if constexpr (MODE == 1){
        float v[NT];
        float ss = 0.f;
        if (row < n){
          #pragma unroll
          for (int nt=0;nt<NT;nt++){
            float u = acc[mt][nt][r] + bf2f(addb[(size_t)row*DOUT + nt*16 + c]);
            u = u*scv[nt] + shv[nt];
            v[nt] = u;
            ss += u*u;
          }
        } else {
          #pragma unroll
          for (int nt=0;nt<NT;nt++) v[nt] = 0.f;
        }
        ss += __shfl_xor(ss, 1, 64);
        ss += __shfl_xor(ss, 2, 64);
        ss += __shfl_xor(ss, 4, 64);
        ss += __shfl_xor(ss, 8, 64);
        float rn = 1.0f / fmaxf(sqrtf(ss), 1e-12f);
        if (row < n){
          #pragma unroll
          for (int nt=0;nt<NT;nt++) outf[(size_t)row*DOUT + nt*16 + c] = v[nt]*rn;
        }
      } else {
        if (row < n){
          #pragma unroll
          for (int nt=0;nt<NT;nt++){
            float u = acc[mt][nt][r];
            if constexpr (MODE == 0){
              u = u*scv[nt] + shv[nt];
              u = fmaxf(u, 0.f);
            }
            outb[(size_t)row*DOUT + nt*16 + c] = f2bf(u);
          }
        }
      }
    }
  }
}

// ---------------- launcher ----------------

extern "C" void kernel_launch(void* const* d_in, const int* in_sizes, int n_in,
                              void* d_out, int out_size, void* d_ws, size_t ws_size,
                              hipStream_t stream){
  const float* x = (const float*)d_in[0];
  const int* ei  = (const int*)d_in[1];
  int N = in_sizes[0] / 128;
  int E = in_sizes[1] / 2;
  const int* esrc = ei;
  const int* edst = ei + E;
  int nbuck = CDIV(N, 128);

  const float *Wl[3], *bl[3], *Wr[3], *g[3], *bb[3], *rm[3], *rv[3];
  int dout[3];
  for (int i=0;i<3;i++){
    int base = 2 + 7*i;
    Wl[i]=(const float*)d_in[base];   bl[i]=(const float*)d_in[base+1];
    Wr[i]=(const float*)d_in[base+2]; g[i] =(const float*)d_in[base+3];
    bb[i]=(const float*)d_in[base+4]; rm[i]=(const float*)d_in[base+5];
    rv[i]=(const float*)d_in[base+6];
    dout[i] = in_sizes[base] / 128;
  }

  char* p = (char*)d_ws;
  size_t o = 0;
  auto alloc = [&](size_t bytes)->void*{ void* r = p + o; o += (bytes + 255) & ~(size_t)255; return r; };
  int* bz    = (int*)alloc((size_t)2*nbuck*4);   // bcnt | bcur (one memset)
  int* bcnt  = bz;
  int* bcur  = bz + nbuck;
  int* bbase = (int*)alloc((size_t)(nbuck+1)*4);
  int* off   = (int*)alloc((size_t)(N+1)*4);
  int* csr   = (int*)alloc((size_t)E*4);
  unsigned* ebuf = (unsigned*)alloc((size_t)E*4);
  unsigned* xb   = (unsigned*)alloc((size_t)N*64*4);
  unsigned* mb   = (unsigned*)alloc((size_t)N*64*4);
  unsigned* h_a  = (unsigned*)alloc((size_t)N*64*4);
  unsigned* h_b  = (unsigned*)alloc((size_t)N*64*4);
  unsigned* ylb  = (unsigned*)alloc((size_t)N*32*4);
  unsigned* myl  = (unsigned*)alloc((size_t)N*32*4);
  unsigned short* Bpk01[2];
  float* sc[3]; float* sh[3];
  for (int i=0;i<2;i++) Bpk01[i] = (unsigned short*)alloc((size_t)256*dout[i]*2);
  unsigned short* BpkL = (unsigned short*)alloc((size_t)128*dout[2]*2);
  unsigned short* BpkR = (unsigned short*)alloc((size_t)128*dout[2]*2);
  for (int i=0;i<3;i++){
    sc[i] = (float*)alloc((size_t)dout[i]*4);
    sh[i] = (float*)alloc((size_t)dout[i]*4);
  }

  hipMemsetAsync(bz, 0, (size_t)2*nbuck*4, stream);

  int castBlocks = CDIV(N*64, 256);
  int histBlocks = CDIV(E, 256*16);
  k_prep   <<<castBlocks + histBlocks,256,0,stream>>>(x, N*64, xb, edst, E, bcnt, nbuck, castBlocks);
  k_bscan  <<<1,256,0,stream>>>(bcnt, nbuck, bbase);
  k_bucketA<<<CDIV(E,256*16),256,0,stream>>>(esrc, edst, E, bbase, bcur, ebuf, nbuck);
  k_bucketB<<<nbuck,256,0,stream>>>(ebuf, bbase, N, off, csr);

  WtpArgs wa[4];
  wa[0] = { Wl[0], Wr[0], bl[0], g[0], bb[0], rm[0], rv[0], Bpk01[0], sc[0], sh[0], 8, dout[0], 1, CDIV(256*dout[0]+dout[0],256) };
  wa[1] = { Wl[1], Wr[1], bl[1], g[1], bb[1], rm[1], rv[1], Bpk01[1], sc[1], sh[1], 8, dout[1], 1, CDIV(256*dout[1]+dout[1],256) };
  wa[2] = { Wl[2], nullptr, nullptr, nullptr, nullptr, nullptr, nullptr, BpkL, nullptr, nullptr, 4, dout[2], 0, CDIV(128*dout[2],256) };
  wa[3] = { Wr[2], nullptr, bl[2], g[2], bb[2], rm[2], rv[2], BpkR, sc[2], sh[2], 4, dout[2], 1, CDIV(128*dout[2]+dout[2],256) };
  k_wtp_all<<<wa[0].nblk + wa[1].nblk + wa[2].nblk + wa[3].nblk,256,0,stream>>>(wa[0], wa[1], wa[2], wa[3]);

  // layers 0,1: agg(128-dim) then dual-K GEMM
  const unsigned* ins[2] = { xb, h_a };
  unsigned* outs[2] = { h_a, h_b };
  for (int i=0;i<2;i++){
    k_agg<<<CDIV(N*16,256),256,0,stream>>>((const uint4*)ins[i], off, csr, N, (uint4*)mb);
    k_gemm_mfma<128,8,0><<<CDIV(N,128),256,0,stream>>>((const unsigned short*)mb, (const unsigned short*)ins[i],
                                                       Bpk01[i], sc[i], sh[i], nullptr,
                                                       nullptr, (unsigned short*)outs[i], N);
  }
  // layer 2: yl = h_b @ Wl^T; mean-agg yl (64-dim); final = BN(mean_yl + h_b@Wr^T) + L2norm
  k_gemm_mfma<64,4,2><<<CDIV(N,128),256,0,stream>>>((const unsigned short*)h_b, nullptr,
                                                    BpkL, nullptr, nullptr, nullptr,
                                                    nullptr, (unsigned short*)ylb, N);
  k_agg64<<<CDIV(N*8,256),256,0,stream>>>((const uint4*)ylb, off, csr, N, (uint4*)myl);
  k_gemm_mfma<64,4,1><<<CDIV(N,128),256,0,stream>>>((const unsigned short*)h_b, nullptr,
                                                    BpkR, sc[2], sh[2], (const unsigned short*)myl,
                                                    (float*)d_out, nullptr, N);
}

// Round 6
// 270.221 us; speedup vs baseline: 1.0658x; 1.0658x over previous
//
#include <hip/hip_runtime.h>
#include <hip/hip_bf16.h>

#define CDIV(a,b) (((a)+(b)-1)/(b))
#define NBUCK_MAX 512   // buckets of 128 nodes; supports N up to 65536 (ebuf packing needs N<=65536)

typedef __attribute__((ext_vector_type(8))) short short8;
typedef __attribute__((ext_vector_type(4))) float f32x4;

static __device__ __forceinline__ unsigned short f2bf(float f){
  union { float f; unsigned u; } v; v.f = f;
  unsigned r = v.u + 0x7fffu + ((v.u >> 16) & 1u);   // RNE
  return (unsigned short)(r >> 16);
}
static __device__ __forceinline__ unsigned pack2(float lo, float hi){
  return (unsigned)f2bf(lo) | ((unsigned)f2bf(hi) << 16);
}
static __device__ __forceinline__ float bfu_lo(unsigned u){
  union { unsigned u; float f; } v; v.u = u << 16; return v.f;
}
static __device__ __forceinline__ float bfu_hi(unsigned u){
  union { unsigned u; float f; } v; v.u = u & 0xffff0000u; return v.f;
}
static __device__ __forceinline__ float bf2f(unsigned short s){
  union { unsigned u; float f; } v; v.u = ((unsigned)s) << 16; return v.f;
}

// ---------------- weight pack args ----------------

struct WtpArgs {
  const float *W0, *W1, *bl, *g, *b, *rm, *rv;
  unsigned short* Bpk; float *sc; float *sh;
  int kblk, dout, do_bn, nblk;
};

static __device__ __forceinline__ void wtp_one(const WtpArgs& a, int idx){
  int NB16 = a.kblk*32*a.dout;
  if (idx < NB16){
    int j = idx & 7, lane = (idx >> 3) & 63, rest = idx >> 9;
    int NT = a.dout >> 4;
    int nt = rest % NT, kk = rest / NT;
    int nn = nt*16 + (lane & 15);
    int k  = kk*32 + ((lane >> 4) * 8) + j;
    float v = (k < 128) ? a.W0[nn*128 + k] : a.W1[nn*128 + (k - 128)];
    a.Bpk[idx] = f2bf(v);
  } else if (a.do_bn && idx < NB16 + a.dout){
    int jj = idx - NB16;
    float s = a.g[jj] * rsqrtf(a.rv[jj] + 1e-5f);
    a.sc[jj] = s;
    a.sh[jj] = (a.bl[jj] - a.rm[jj]) * s + a.b[jj];
  }
}

// ---------------- prep: cast x->bf16 | bucket histogram | weight pack, one launch ----------------

__global__ __launch_bounds__(256) void k_prep(const float* __restrict__ x, int n2, unsigned* __restrict__ xb,
                                              const int* __restrict__ dst, int E,
                                              int* __restrict__ bcnt, int nbuck,
                                              int castBlocks, int histBlocks,
                                              WtpArgs a0, WtpArgs a1, WtpArgs a2, WtpArgs a3){
  __shared__ int s[NBUCK_MAX];
  int b = blockIdx.x, t = threadIdx.x;
  if (b < castBlocks){
    int i = b*256 + t;
    if (i < n2){
      float2 v = ((const float2*)x)[i];
      xb[i] = pack2(v.x, v.y);
    }
    return;
  }
  b -= castBlocks;
  if (b < histBlocks){
    for (int i=t;i<nbuck;i+=256) s[i] = 0;
    __syncthreads();
    constexpr int EPT = 16;
    int e0 = b*256*EPT;
    #pragma unroll
    for (int i=0;i<EPT;i++){
      int e = e0 + i*256 + t;
      if (e < E) atomicAdd(&s[dst[e] >> 7], 1);
    }
    __syncthreads();
    for (int i=t;i<nbuck;i+=256){
      int c = s[i];
      if (c > 0) atomicAdd(&bcnt[i], c);
    }
    return;
  }
  b -= histBlocks;
  if (b < a0.nblk){ wtp_one(a0, b*256 + t); return; }
  b -= a0.nblk;
  if (b < a1.nblk){ wtp_one(a1, b*256 + t); return; }
  b -= a1.nblk;
  if (b < a2.nblk){ wtp_one(a2, b*256 + t); return; }
  b -= a2.nblk;
  wtp_one(a3, b*256 + t);
}

// single block: exclusive scan of bcnt[0..nbuck) -> bbase[0..nbuck], bbase[nbuck]=E
__global__ __launch_bounds__(256) void k_bscan(const int* __restrict__ bcnt, int nbuck,
                                               int* __restrict__ bbase){
  __shared__ int s[256];
  int t = threadIdx.x;
  int a0 = (2*t   < nbuck) ? bcnt[2*t]   : 0;
  int a1 = (2*t+1 < nbuck) ? bcnt[2*t+1] : 0;
  s[t] = a0 + a1; __syncthreads();
  for (int d=1; d<256; d<<=1){
    int u = (t>=d) ? s[t-d] : 0;
    __syncthreads();
    s[t] += u;
    __syncthreads();
  }
  int excl = s[t] - (a0 + a1);
  if (2*t   < nbuck) bbase[2*t]   = excl;
  if (2*t+1 < nbuck) bbase[2*t+1] = excl + a0;
  if (t == 255) bbase[nbuck] = s[255];
}

// Pass A: bin edges into 128-node buckets; bucket region in ebuf == final csr region.
// Packed entry: (local_dst << 16) | src  (requires N <= 65536)
__global__ __launch_bounds__(256) void k_bucketA(const int* __restrict__ src, const int* __restrict__ dst,
                                                 int E, const int* __restrict__ bbase,
                                                 int* __restrict__ bcur, unsigned* __restrict__ ebuf, int nbuck){
  __shared__ int scnt[NBUCK_MAX];
  __shared__ int sbase[NBUCK_MAX];
  __shared__ int sboff[NBUCK_MAX];
  int t = threadIdx.x;
  for (int i=t;i<nbuck;i+=256) scnt[i] = 0;
  __syncthreads();
  constexpr int EPT = 16;
  int e0 = blockIdx.x*256*EPT;
  int b[EPT]; unsigned pk[EPT];
  #pragma unroll
  for (int i=0;i<EPT;i++){
    int e = e0 + i*256 + t;
    if (e < E){
      int d = dst[e];
      b[i] = d >> 7;
      pk[i] = ((unsigned)(d & 127) << 16) | (unsigned)src[e];
      atomicAdd(&scnt[b[i]], 1);
    } else b[i] = -1;
  }
  __syncthreads();
  for (int i=t;i<nbuck;i+=256){
    int c = scnt[i];
    sbase[i] = (c > 0) ? atomicAdd(&bcur[i], c) : 0;
    sboff[i] = bbase[i];
    scnt[i] = 0;
  }
  __syncthreads();
  #pragma unroll
  for (int i=0;i<EPT;i++){
    if (b[i] >= 0){
      int p = atomicAdd(&scnt[b[i]], 1);
      ebuf[(size_t)sboff[b[i]] + sbase[b[i]] + p] = pk[i];
    }
  }
}

// Pass B: one block per bucket; local degree count + scan -> off + csr scatter in ~8KB window.
__global__ __launch_bounds__(256) void k_bucketB(const unsigned* __restrict__ ebuf, const int* __restrict__ bbase,
                                                 int N, int* __restrict__ off, int* __restrict__ csr){
  int b = blockIdx.x;
  int n0 = b << 7, n1 = min(n0 + 128, N);
  __shared__ int sdeg[128];
  __shared__ int sabs[129];
  __shared__ int cur[128];
  int t = threadIdx.x;
  if (t < 128){ sdeg[t] = 0; cur[t] = 0; }
  __syncthreads();
  int e0 = bbase[b], e1 = bbase[b+1];
  for (int e = e0 + t; e < e1; e += 256)
    atomicAdd(&sdeg[ebuf[e] >> 16], 1);
  __syncthreads();
  for (int d=1; d<128; d<<=1){
    int u = (t < 128 && t >= d) ? sdeg[t-d] : 0;
    __syncthreads();
    if (t < 128) sdeg[t] += u;
    __syncthreads();
  }
  if (t == 0) sabs[0] = e0;
  if (t < 128) sabs[t+1] = e0 + sdeg[t];
  __syncthreads();
  if (t <= n1 - n0) off[n0 + t] = sabs[t];
  for (int e = e0 + t; e < e1; e += 256){
    unsigned pr = ebuf[e];
    int ln = (int)(pr >> 16);
    int p = atomicAdd(&cur[ln], 1);
    csr[sabs[ln] + p] = (int)(pr & 0xffffu);
  }
}

// ---------------- mean aggregation, 128-dim rows: 4 nodes/wave, 16 lanes x uint4, 8-deep unroll ----------------

#define ACC8(v) { a0 += bfu_lo(v.x); a1 += bfu_hi(v.x); a2 += bfu_lo(v.y); a3 += bfu_hi(v.y); \
                  a4 += bfu_lo(v.z); a5 += bfu_hi(v.z); a6 += bfu_lo(v.w); a7 += bfu_hi(v.w); }

__global__ __launch_bounds__(256) void k_agg(const uint4* __restrict__ hin4, const int* __restrict__ off,
                                             const int* __restrict__ csr, int n, uint4* __restrict__ mean4){
  int tid = blockIdx.x*256 + threadIdx.x;
  int lane = threadIdx.x & 63;
  int sl = lane & 15;
  int node = (tid >> 6)*4 + (lane >> 4);
  bool valid = node < n;
  int s0 = valid ? off[node]   : 0;
  int s1 = valid ? off[node+1] : 0;
  float a0=0,a1=0,a2=0,a3=0,a4=0,a5=0,a6=0,a7=0;
  int e = s0;
  for (; e + 8 <= s1; e += 8){
    int i0 = csr[e],   i1 = csr[e+1], i2 = csr[e+2], i3 = csr[e+3];
    int i4 = csr[e+4], i5 = csr[e+5], i6 = csr[e+6], i7 = csr[e+7];
    uint4 v0 = hin4[(size_t)i0*16 + sl];
    uint4 v1 = hin4[(size_t)i1*16 + sl];
    uint4 v2 = hin4[(size_t)i2*16 + sl];
    uint4 v3 = hin4[(size_t)i3*16 + sl];
    uint4 v4 = hin4[(size_t)i4*16 + sl];
    uint4 v5 = hin4[(size_t)i5*16 + sl];
    uint4 v6 = hin4[(size_t)i6*16 + sl];
    uint4 v7 = hin4[(size_t)i7*16 + sl];
    ACC8(v0); ACC8(v1); ACC8(v2); ACC8(v3);
    ACC8(v4); ACC8(v5); ACC8(v6); ACC8(v7);
  }
  for (; e + 4 <= s1; e += 4){
    int i0 = csr[e], i1 = csr[e+1], i2 = csr[e+2], i3 = csr[e+3];
    uint4 v0 = hin4[(size_t)i0*16 + sl];
    uint4 v1 = hin4[(size_t)i1*16 + sl];
    uint4 v2 = hin4[(size_t)i2*16 + sl];
    uint4 v3 = hin4[(size_t)i3*16 + sl];
    ACC8(v0); ACC8(v1); ACC8(v2); ACC8(v3);
  }
  for (; e < s1; e++){
    uint4 v = hin4[(size_t)csr[e]*16 + sl];
    ACC8(v);
  }
  if (valid){
    int d = s1 - s0;
    float inv = 1.0f / (float)(d > 0 ? d : 1);
    uint4 o;
    o.x = pack2(a0*inv, a1*inv);
    o.y = pack2(a2*inv, a3*inv);
    o.z = pack2(a4*inv, a5*inv);
    o.w = pack2(a6*inv, a7*inv);
    mean4[(size_t)node*16 + sl] = o;
  }
}

// ---------------- hidden-layer GEMM (LDS-staged B, round-4 structure), optional fused yl mini-GEMM ----------------
// C[N][128] = [A0|A1]@B (K=256), BN+ReLU, bf16 out. If YL: also yl = C@Wl2^T (K=128, DOUT=64) -> outyl.

template<bool YL>
__global__ __launch_bounds__(256, 2) void k_gemm_hid(
    const unsigned short* __restrict__ A0, const unsigned short* __restrict__ A1,
    const unsigned short* __restrict__ Bpk, const float* __restrict__ sc,
    const float* __restrict__ sh, const unsigned short* __restrict__ BpkL,
    unsigned short* __restrict__ outh, unsigned short* __restrict__ outyl, int n){
  __shared__ unsigned short Bs[256*128];   // 64 KB
  int t = threadIdx.x;
  {
    const uint4* s = (const uint4*)Bpk;
    uint4* d = (uint4*)Bs;
    #pragma unroll
    for (int i=0;i<16;i++) d[i*256 + t] = s[i*256 + t];
  }
  __syncthreads();

  int lane = t & 63, w = t >> 6;
  int quad = lane >> 4, c = lane & 15;
  int mb = blockIdx.x*128, woff = w*32;
  int r0 = mb + woff + c;
  int r1 = r0 + 16;

  f32x4 acc[2][8];
  #pragma unroll
  for (int mt=0;mt<2;mt++)
    #pragma unroll
    for (int nt=0;nt<8;nt++) acc[mt][nt] = (f32x4){0.f,0.f,0.f,0.f};

  #pragma unroll
  for (int kk=0; kk<8; kk++){
    const unsigned short* ab = (kk >= 4) ? A1 : A0;
    int ka = (kk & 3)*32 + quad*8;
    short8 a0 = {0,0,0,0,0,0,0,0}, a1 = {0,0,0,0,0,0,0,0};
    if (r0 < n) a0 = *(const short8*)(ab + (size_t)r0*128 + ka);
    if (r1 < n) a1 = *(const short8*)(ab + (size_t)r1*128 + ka);
    #pragma unroll
    for (int nt=0; nt<8; nt++){
      short8 b = *(const short8*)&Bs[(size_t)((kk*8 + nt)*64 + lane)*8];
      acc[0][nt] = __builtin_amdgcn_mfma_f32_16x16x32_bf16(a0, b, acc[0][nt], 0, 0, 0);
      acc[1][nt] = __builtin_amdgcn_mfma_f32_16x16x32_bf16(a1, b, acc[1][nt], 0, 0, 0);
    }
  }

  float scv[8], shv[8];
  #pragma unroll
  for (int nt=0;nt<8;nt++){ scv[nt] = sc[nt*16 + c]; shv[nt] = sh[nt*16 + c]; }

  #pragma unroll
  for (int mt=0; mt<2; mt++){
    #pragma unroll
    for (int r=0;r<4;r++){
      int row = mb + woff + mt*16 + quad*4 + r;
      if (row < n){
        #pragma unroll
        for (int nt=0;nt<8;nt++){
          float u = acc[mt][nt][r]*scv[nt] + shv[nt];
          u = fmaxf(u, 0.f);
          outh[(size_t)row*128 + nt*16 + c] = f2bf(u);
        }
      }
    }
  }

  if constexpr (YL){
    __syncthreads();   // everyone done reading Bs; outh tile visible block-wide after barrier
    {
      // restage own h tile (128 rows x 128 bf16 = 2048 uint4) into Bs[0..16384)
      uint4* d = (uint4*)Bs;
      const uint4* s4 = (const uint4*)outh;
      #pragma unroll
      for (int i=0;i<8;i++){
        int idx = i*256 + t;
        int row = idx >> 4;
        int gr = mb + row; if (gr > n-1) gr = n-1;
        d[idx] = s4[(size_t)gr*16 + (idx & 15)];
      }
      // stage BpkL (128x64 = 1024 uint4) at short-offset 16384
      const uint4* sL = (const uint4*)BpkL;
      #pragma unroll
      for (int i=0;i<4;i++) d[2048 + i*256 + t] = sL[i*256 + t];
    }
    __syncthreads();
    f32x4 acc2[2][4];
    #pragma unroll
    for (int mt=0;mt<2;mt++)
      #pragma unroll
      for (int nt=0;nt<4;nt++) acc2[mt][nt] = (f32x4){0.f,0.f,0.f,0.f};
    int r0l = woff + c, r1l = r0l + 16;
    #pragma unroll
    for (int kk=0; kk<4; kk++){
      int ka = kk*32 + quad*8;
      short8 a0 = *(const short8*)&Bs[(size_t)r0l*128 + ka];
      short8 a1 = *(const short8*)&Bs[(size_t)r1l*128 + ka];
      #pragma unroll
      for (int nt=0; nt<4; nt++){
        short8 b = *(const short8*)&Bs[16384 + (size_t)((kk*4 + nt)*64 + lane)*8];
        acc2[0][nt] = __builtin_amdgcn_mfma_f32_16x16x32_bf16(a0, b, acc2[0][nt], 0, 0, 0);
        acc2[1][nt] = __builtin_amdgcn_mfma_f32_16x16x32_bf16(a1, b, acc2[1][nt], 0, 0, 0);
      }
    }
    #pragma unroll
    for (int mt=0; mt<2; mt++){
      #pragma unroll
      for (int r=0;r<4;r++){
        int row = mb + woff + mt*16 + quad*4 + r;
        if (row < n){
          #pragma unroll
          for (int nt=0;nt<4;nt++) outyl[(size_t)row*64 + nt*16 + c] = f2bf(acc2[mt][nt][r]);
        }
      }
    }
  }
}

// ---------------- fused layer-3: mean-yl gather (64-dim) + GEMM (h_b@Wr2^T) + BN + L2norm ----------------

__global__ __launch_bounds__(256, 2) void k_aggf(
    const uint4* __restrict__ ylb4, const int* __restrict__ off, const int* __restrict__ csr,
    const unsigned short* __restrict__ A0, const unsigned short* __restrict__ BpkR,
    const float* __restrict__ sc, const float* __restrict__ sh,
    float* __restrict__ outf, int n){
  __shared__ unsigned short Ms[128*64];   // 16 KB mean-yl tile
  __shared__ unsigned short Bs[128*64];   // 16 KB BpkR
  int t = threadIdx.x;
  {
    const uint4* s = (const uint4*)BpkR;
    uint4* d = (uint4*)Bs;
    #pragma unroll
    for (int i=0;i<4;i++) d[i*256 + t] = s[i*256 + t];
  }
  int lane = t & 63, w = t >> 6;
  int mb = blockIdx.x*128;
  int sl8 = lane & 7;

  // gather phase: wave w covers local rows [w*32, w*32+32), 8 nodes at a time
  #pragma unroll
  for (int it=0; it<4; it++){
    int ln = w*32 + it*8 + (lane >> 3);
    int node = mb + ln;
    bool valid = node < n;
    int s0 = valid ? off[node]   : 0;
    int s1 = valid ? off[node+1] : 0;
    float a0=0,a1=0,a2=0,a3=0,a4=0,a5=0,a6=0,a7=0;
    int e = s0;
    for (; e + 4 <= s1; e += 4){
      int i0 = csr[e], i1 = csr[e+1], i2 = csr[e+2], i3 = csr[e+3];
      uint4 v0 = ylb4[(size_t)i0*8 + sl8];
      uint4 v1 = ylb4[(size_t)i1*8 + sl8];
      uint4 v2 = ylb4[(size_t)i2*8 + sl8];
      uint4 v3 = ylb4[(size_t)i3*8 + sl8];
      ACC8(v0); ACC8(v1); ACC8(v2); ACC8(v3);
    }
    for (; e < s1; e++){
      uint4 v = ylb4[(size_t)csr[e]*8 + sl8];
      ACC8(v);
    }
    int d = s1 - s0;
    float inv = 1.0f / (float)(d > 0 ? d : 1);
    uint4 o;
    o.x = pack2(a0*inv, a1*inv);
    o.y = pack2(a2*inv, a3*inv);
    o.z = pack2(a4*inv, a5*inv);
    o.w = pack2(a6*inv, a7*inv);
    ((uint4*)Ms)[ln*8 + sl8] = o;
  }
  __syncthreads();

  // GEMM phase: C = h_b @ Wr2^T (K=128), + mean-yl, BN, L2-normalize
  int quad = lane >> 4, c = lane & 15;
  int woff = w*32;
  int r0 = mb + woff + c;
  int r1 = r0 + 16;
  f32x4 acc[2][4];
  #pragma unroll
  for (int mt=0;mt<2;mt++)
    #pragma unroll
    for (int nt=0;nt<4;nt++) acc[mt][nt] = (f32x4){0.f,0.f,0.f,0.f};
  #pragma unroll
  for (int kk=0; kk<4; kk++){
    int ka = kk*32 + quad*8;
    short8 a0 = {0,0,0,0,0,0,0,0}, a1 = {0,0,0,0,0,0,0,0};
    if (r0 < n) a0 = *(const short8*)(A0 + (size_t)r0*128 + ka);
    if (r1 < n) a1 = *(const short8*)(A0 + (size_t)r1*128 + ka);
    #pragma unroll
    for (int nt=0; nt<4; nt++){
      short8 b = *(const short8*)&Bs[(size_t)((kk*4 + nt)*64 + lane)*8];
      acc[0][nt] = __builtin_amdgcn_mfma_f32_16x16x32_bf16(a0, b, acc[0][nt], 0, 0, 0);
      acc[1][nt] = __builtin_amdgcn_mfma_f32_16x16x32_bf16(a1, b, acc[1][nt], 0, 0, 0);
    }
  }

  float scv[4], shv[4];
  #pragma unroll
  for (int nt=0;nt<4;nt++){ scv[nt] = sc[nt*16 + c]; shv[nt] = sh[nt*16 + c]; }

  #pragma unroll
  for (int mt=0; mt<2; mt++){
    #pragma unroll
    for (int r=0;r<4;r++){
      int lr = woff + mt*16 + quad*4 + r;
      int row = mb + lr;
      float v[4];
      float ss = 0.f;
      if (row < n){
        #pragma unroll
        for (int nt=0;nt<4;nt++){
          float u = acc[mt][nt][r] + bf2f(Ms[lr*64 + nt*16 + c]);
          u = u*scv[nt] + shv[nt];
          v[nt] = u;
          ss += u*u;
        }
      } else {
        #pragma unroll
        for (int nt=0;nt<4;nt++) v[nt] = 0.f;
      }
      ss += __shfl_xor(ss, 1, 64);
      ss += __shfl_xor(ss, 2, 64);
      ss += __shfl_xor(ss, 4, 64);
      ss += __shfl_xor(ss, 8, 64);
      float rn = 1.0f / fmaxf(sqrtf(ss), 1e-12f);
      if (row < n){
        #pragma unroll
        for (int nt=0;nt<4;nt++) outf[(size_t)row*64 + nt*16 + c] = v[nt]*rn;
      }
    }
  }
}

// ---------------- launcher ----------------

extern "C" void kernel_launch(void* const* d_in, const int* in_sizes, int n_in,
                              void* d_out, int out_size, void* d_ws, size_t ws_size,
                              hipStream_t stream){
  const float* x = (const float*)d_in[0];
  const int* ei  = (const int*)d_in[1];
  int N = in_sizes[0] / 128;
  int E = in_sizes[1] / 2;
  const int* esrc = ei;
  const int* edst = ei + E;
  int nbuck = CDIV(N, 128);

  const float *Wl[3], *bl[3], *Wr[3], *g[3], *bb[3], *rm[3], *rv[3];
  int dout[3];
  for (int i=0;i<3;i++){
    int base = 2 + 7*i;
    Wl[i]=(const float*)d_in[base];   bl[i]=(const float*)d_in[base+1];
    Wr[i]=(const float*)d_in[base+2]; g[i] =(const float*)d_in[base+3];
    bb[i]=(const float*)d_in[base+4]; rm[i]=(const float*)d_in[base+5];
    rv[i]=(const float*)d_in[base+6];
    dout[i] = in_sizes[base] / 128;
  }

  char* p = (char*)d_ws;
  size_t o = 0;
  auto alloc = [&](size_t bytes)->void*{ void* r = p + o; o += (bytes + 255) & ~(size_t)255; return r; };
  int* bz    = (int*)alloc((size_t)2*nbuck*4);   // bcnt | bcur (one memset)
  int* bcnt  = bz;
  int* bcur  = bz + nbuck;
  int* bbase = (int*)alloc((size_t)(nbuck+1)*4);
  int* off   = (int*)alloc((size_t)(N+1)*4);
  int* csr   = (int*)alloc((size_t)E*4);
  unsigned* ebuf = (unsigned*)alloc((size_t)E*4);
  unsigned* xb   = (unsigned*)alloc((size_t)N*64*4);
  unsigned* mb   = (unsigned*)alloc((size_t)N*64*4);
  unsigned* h_a  = (unsigned*)alloc((size_t)N*64*4);
  unsigned* h_b  = (unsigned*)alloc((size_t)N*64*4);
  unsigned* ylb  = (unsigned*)alloc((size_t)N*32*4);
  unsigned short* Bpk01[2];
  float* sc[3]; float* sh[3];
  for (int i=0;i<2;i++) Bpk01[i] = (unsigned short*)alloc((size_t)256*dout[i]*2);
  unsigned short* BpkL = (unsigned short*)alloc((size_t)128*dout[2]*2);
  unsigned short* BpkR = (unsigned short*)alloc((size_t)128*dout[2]*2);
  for (int i=0;i<3;i++){
    sc[i] = (float*)alloc((size_t)dout[i]*4);
    sh[i] = (float*)alloc((size_t)dout[i]*4);
  }

  hipMemsetAsync(bz, 0, (size_t)2*nbuck*4, stream);

  WtpArgs wa[4];
  wa[0] = { Wl[0], Wr[0], bl[0], g[0], bb[0], rm[0], rv[0], Bpk01[0], sc[0], sh[0], 8, dout[0], 1, CDIV(256*dout[0]+dout[0],256) };
  wa[1] = { Wl[1], Wr[1], bl[1], g[1], bb[1], rm[1], rv[1], Bpk01[1], sc[1], sh[1], 8, dout[1], 1, CDIV(256*dout[1]+dout[1],256) };
  wa[2] = { Wl[2], nullptr, nullptr, nullptr, nullptr, nullptr, nullptr, BpkL, nullptr, nullptr, 4, dout[2], 0, CDIV(128*dout[2],256) };
  wa[3] = { Wr[2], nullptr, bl[2], g[2], bb[2], rm[2], rv[2], BpkR, sc[2], sh[2], 4, dout[2], 1, CDIV(128*dout[2]+dout[2],256) };

  int castBlocks = CDIV(N*64, 256);
  int histBlocks = CDIV(E, 256*16);
  int prepBlocks = castBlocks + histBlocks + wa[0].nblk + wa[1].nblk + wa[2].nblk + wa[3].nblk;
  k_prep   <<<prepBlocks,256,0,stream>>>(x, N*64, xb, edst, E, bcnt, nbuck, castBlocks, histBlocks,
                                         wa[0], wa[1], wa[2], wa[3]);
  k_bscan  <<<1,256,0,stream>>>(bcnt, nbuck, bbase);
  k_bucketA<<<CDIV(E,256*16),256,0,stream>>>(esrc, edst, E, bbase, bcur, ebuf, nbuck);
  k_bucketB<<<nbuck,256,0,stream>>>(ebuf, bbase, N, off, csr);

  // layer 0
  k_agg<<<CDIV(N*16,256),256,0,stream>>>((const uint4*)xb, off, csr, N, (uint4*)mb);
  k_gemm_hid<false><<<CDIV(N,128),256,0,stream>>>((const unsigned short*)mb, (const unsigned short*)xb,
                                                  Bpk01[0], sc[0], sh[0], nullptr,
                                                  (unsigned short*)h_a, nullptr, N);
  // layer 1 (+ fused yl = h_b @ Wl2^T)
  k_agg<<<CDIV(N*16,256),256,0,stream>>>((const uint4*)h_a, off, csr, N, (uint4*)mb);
  k_gemm_hid<true><<<CDIV(N,128),256,0,stream>>>((const unsigned short*)mb, (const unsigned short*)h_a,
                                                 Bpk01[1], sc[1], sh[1], BpkL,
                                                 (unsigned short*)h_b, (unsigned short*)ylb, N);
  // layer 2: fused mean-yl gather + final GEMM + BN + L2norm
  k_aggf<<<CDIV(N,128),256,0,stream>>>((const uint4*)ylb, off, csr,
                                       (const unsigned short*)h_b, BpkR, sc[2], sh[2],
                                       (float*)d_out, N);
}